// Round 16
// baseline (384.825 us; speedup 1.0000x reference)
//
#include <hip/hip_runtime.h>
#include <hip/hip_bf16.h>

#define DEPTH  4
#define NH     8
#define DMODEL 256
#define HD     32
#define MLPD   1024
#define SEQ    2048
#define BATCH  4
#define NTOK   (BATCH*SEQ)

typedef __attribute__((ext_vector_type(8))) short s8v;   // 8 bf16 (MFMA A/B frag)
typedef __attribute__((ext_vector_type(4))) short s4v;
typedef __attribute__((ext_vector_type(4))) float f4v;   // 16x16 MFMA C/D frag
typedef __attribute__((ext_vector_type(16))) float f16v; // 32x32 MFMA C/D frag

#if __has_builtin(__builtin_amdgcn_exp2f)
#define EXP2(x) __builtin_amdgcn_exp2f(x)
#else
#define EXP2(x) exp2f(x)
#endif

__device__ __forceinline__ short f2bf(float f) {
    union { float f; unsigned u; } v; v.f = f;
    unsigned r = v.u + 0x7fffu + ((v.u >> 16) & 1u);   // RNE
    return (short)(r >> 16);
}

__device__ __forceinline__ f4v mfma16(s8v a, s8v b, f4v c) {
    return __builtin_amdgcn_mfma_f32_16x16x32_bf16(a, b, c, 0, 0, 0);
}
__device__ __forceinline__ f16v mfma32(s8v a, s8v b, f16v c) {
    return __builtin_amdgcn_mfma_f32_32x32x16_bf16(a, b, c, 0, 0, 0);
}

__device__ __forceinline__ void glds16(const short* g, short* l) {
    __builtin_amdgcn_global_load_lds(
        (const __attribute__((address_space(1))) void*)g,
        (__attribute__((address_space(3))) void*)l, 16, 0, 0);
}

// counted-vmcnt barrier: do NOT drain the in-flight prefetch (T4).
#define WAITBAR(NLIT)                                                       \
    do {                                                                    \
        __builtin_amdgcn_sched_barrier(0);                                  \
        asm volatile("s_waitcnt vmcnt(" NLIT ")" ::: "memory");             \
        __builtin_amdgcn_s_barrier();                                       \
        __builtin_amdgcn_sched_barrier(0);                                  \
    } while (0)

// ---------------- weight transpose + f32->bf16 ----------------
__global__ void transpose_cvt(const float* __restrict__ src, short* __restrict__ dst,
                              int K, int N) {
    __shared__ float tile[32][33];
    const int l = blockIdx.z;
    src += (size_t)l * K * N;
    dst += (size_t)l * N * K;
    const int n0 = blockIdx.x * 32, k0 = blockIdx.y * 32;
    const int tx = threadIdx.x, ty = threadIdx.y;   // 32 x 8
    #pragma unroll
    for (int i = 0; i < 32; i += 8)
        tile[ty + i][tx] = src[(size_t)(k0 + ty + i) * N + n0 + tx];
    __syncthreads();
    #pragma unroll
    for (int i = 0; i < 32; i += 8)
        dst[(size_t)(n0 + ty + i) * K + k0 + tx] = f2bf(tile[tx][ty + i]);
}

// ---------------- LayerNorm: x f32 [NTOK][256] -> bf16 ----------------
__global__ void ln_kernel(const float* __restrict__ x, const float* __restrict__ g,
                          const float* __restrict__ b, short* __restrict__ out) {
    const int row  = blockIdx.x * 4 + (threadIdx.x >> 6);
    const int lane = threadIdx.x & 63;
    const float4 v = *(const float4*)(x + (size_t)row * DMODEL + lane * 4);
    float s = v.x + v.y + v.z + v.w;
    #pragma unroll
    for (int m = 32; m; m >>= 1) s += __shfl_xor(s, m);
    const float mean = s * (1.0f / DMODEL);
    const float dx = v.x - mean, dy = v.y - mean, dz = v.z - mean, dw = v.w - mean;
    float q = dx*dx + dy*dy + dz*dz + dw*dw;
    #pragma unroll
    for (int m = 32; m; m >>= 1) q += __shfl_xor(q, m);
    const float rstd = rsqrtf(q * (1.0f / DMODEL) + 1e-5f);
    const float4 gg = *(const float4*)(g + lane * 4);
    const float4 bb = *(const float4*)(b + lane * 4);
    s4v o;
    o.x = f2bf(dx * rstd * gg.x + bb.x);
    o.y = f2bf(dy * rstd * gg.y + bb.y);
    o.z = f2bf(dz * rstd * gg.z + bb.z);
    o.w = f2bf(dw * rstd * gg.w + bb.w);
    *(s4v*)(out + (size_t)row * DMODEL + lane * 4) = o;
}

#define EPI_QKV  0
#define EPI_RES  1
#define EPI_GELU 2

// -------- shared epilogue (verified R4-R12) --------
template<int EPI>
__device__ __forceinline__ void gemm_epilogue(
        f4v acc[2][2], int trow0, int col0, int N, int g, int c,
        const float* __restrict__ bias, float* __restrict__ resio,
        short* __restrict__ outb,
        short* __restrict__ qb, short* __restrict__ kb, short* __restrict__ vtb) {
    if (EPI == EPI_QKV) {
        #pragma unroll
        for (int mf = 0; mf < 2; mf++) {
            const int tokb = trow0 + mf * 16 + g * 4;
            const int b = tokb >> 11, n = tokb & 2047;
            #pragma unroll
            for (int nf = 0; nf < 2; nf++) {
                const int colg = col0 + nf * 16 + c;
                const int part = colg >> 8, pc = colg & 255;
                const int h = pc >> 5, d = pc & 31;
                const size_t bh = (size_t)(b * NH + h);
                if (part == 2) {
                    s4v pv;
                    #pragma unroll
                    for (int r = 0; r < 4; r++) pv[r] = f2bf(acc[mf][nf][r]);
                    *(s4v*)(vtb + (bh * 32 + d) * SEQ + n) = pv;
                } else {
                    // q pre-scaled by dim^-0.5 * log2(e) so attention can exp2 raw scores
                    const float sc = (part == 0) ? 0.090168440f : 1.0f;
                    short* dst = (part == 0 ? qb : kb) + ((bh << 11) + n) * 32 + d;
                    #pragma unroll
                    for (int r = 0; r < 4; r++) dst[(size_t)r * 32] = f2bf(acc[mf][nf][r] * sc);
                }
            }
        }
    } else if (EPI == EPI_RES) {
        #pragma unroll
        for (int mf = 0; mf < 2; mf++)
            #pragma unroll
            for (int nf = 0; nf < 2; nf++) {
                const int colg = col0 + nf * 16 + c;
                const float bv = bias[colg];
                #pragma unroll
                for (int r = 0; r < 4; r++) {
                    const int row = trow0 + mf * 16 + g * 4 + r;
                    const size_t idx = (size_t)row * N + colg;
                    resio[idx] = resio[idx] + bv + acc[mf][nf][r];
                }
            }
    } else {  // EPI_GELU
        #pragma unroll
        for (int mf = 0; mf < 2; mf++)
            #pragma unroll
            for (int nf = 0; nf < 2; nf++) {
                const int colg = col0 + nf * 16 + c;
                const float bv = bias[colg];
                #pragma unroll
                for (int r = 0; r < 4; r++) {
                    const int row = trow0 + mf * 16 + g * 4 + r;
                    const float v = acc[mf][nf][r] + bv;
                    const float ge = 0.5f * v * (1.0f + erff(v * 0.70710678118f));
                    outb[(size_t)row * N + colg] = f2bf(ge);
                }
            }
    }
}

// ---------------- K=256 GEMM: 3-buffer counted-vmcnt pipeline (R8-verified) ----
template<int EPI>
__global__ __launch_bounds__(256) void gemm_p256(
        const short* __restrict__ A, const short* __restrict__ Bt,
        const int N, const int nbx,
        const float* __restrict__ bias,
        float* __restrict__ resio,
        short* __restrict__ outb,
        short* __restrict__ qb, short* __restrict__ kb, short* __restrict__ vtb) {
    __shared__ short ldsA[3][64 * 64];
    __shared__ short ldsB[3][64 * 64];
    const int nblk = gridDim.x;
    const int bid  = blockIdx.x;
    const int swz  = (bid & 7) * (nblk >> 3) + (bid >> 3);   // XCD-chunked
    const int m0 = (swz / nbx) * 64, n0 = (swz % nbx) * 64;
    const int tid  = threadIdx.x;
    const int wave = tid >> 6, lane = tid & 63;
    const int g = lane >> 4, c = lane & 15;
    const int wm = wave >> 1, wn = wave & 1;

#define STAGEP(buf, k0)                                                     \
    do {                                                                    \
        _Pragma("unroll")                                                   \
        for (int i = 0; i < 2; i++) {                                       \
            const int idx = i * 256 + tid;                                  \
            const int row = idx >> 3, c8 = idx & 7;                         \
            const int gcol = (k0) + ((c8 ^ (row & 7)) * 8);                 \
            glds16(A  + (size_t)(m0 + row) * 256 + gcol, &ldsA[buf][idx*8]);\
            glds16(Bt + (size_t)(n0 + row) * 256 + gcol, &ldsB[buf][idx*8]);\
        }                                                                   \
    } while (0)

#define COMPUTE(buf)                                                        \
    do {                                                                    \
        _Pragma("unroll")                                                   \
        for (int kk = 0; kk < 2; kk++) {                                    \
            s8v af[2], bfr[2];                                              \
            _Pragma("unroll")                                               \
            for (int mf = 0; mf < 2; mf++)                                  \
                af[mf] = *(const s8v*)(&ldsA[buf][(wm*32+mf*16+c)*64 +      \
                                        (((kk<<2)+g) ^ (c&7)) * 8]);        \
            _Pragma("unroll")                                               \
            for (int nf = 0; nf < 2; nf++)                                  \
                bfr[nf] = *(const s8v*)(&ldsB[buf][(wn*32+nf*16+c)*64 +     \
                                        (((kk<<2)+g) ^ (c&7)) * 8]);        \
            _Pragma("unroll")                                               \
            for (int mf = 0; mf < 2; mf++)                                  \
                _Pragma("unroll")                                           \
                for (int nf = 0; nf < 2; nf++)                              \
                    acc[mf][nf] = mfma16(af[mf], bfr[nf], acc[mf][nf]);     \
        }                                                                   \
    } while (0)

    f4v acc[2][2];
    #pragma unroll
    for (int i = 0; i < 2; i++)
        #pragma unroll
        for (int j = 0; j < 2; j++) acc[i][j] = (f4v){0.f, 0.f, 0.f, 0.f};

    STAGEP(0, 0);
    STAGEP(1, 64);
    WAITBAR("4");
    STAGEP(2, 128);
    COMPUTE(0);
    WAITBAR("4");
    STAGEP(0, 192);
    COMPUTE(1);
    WAITBAR("4");
    COMPUTE(2);
    WAITBAR("0");
    COMPUTE(0);
#undef STAGEP
#undef COMPUTE

    gemm_epilogue<EPI>(acc, m0 + wm * 32, n0 + wn * 32, N, g, c,
                       bias, resio, outb, qb, kb, vtb);
}

// ---------------- K=1024 GEMM (FFN2): rolling 3-buffer counted-vmcnt ----------
template<int EPI>
__global__ __launch_bounds__(256) void gemm_p1024(
        const short* __restrict__ A, const short* __restrict__ Bt,
        const int N, const int nbx,
        const float* __restrict__ bias,
        float* __restrict__ resio,
        short* __restrict__ outb) {
    __shared__ short ldsA[3][64 * 64];
    __shared__ short ldsB[3][64 * 64];
    const int nblk = gridDim.x;
    const int bid  = blockIdx.x;
    const int swz  = (bid & 7) * (nblk >> 3) + (bid >> 3);
    const int m0 = (swz / nbx) * 64, n0 = (swz % nbx) * 64;
    const int tid  = threadIdx.x;
    const int wave = tid >> 6, lane = tid & 63;
    const int g = lane >> 4, c = lane & 15;
    const int wm = wave >> 1, wn = wave & 1;

#define STAGEK(buf, k0)                                                     \
    do {                                                                    \
        _Pragma("unroll")                                                   \
        for (int i = 0; i < 2; i++) {                                       \
            const int idx = i * 256 + tid;                                  \
            const int row = idx >> 3, c8 = idx & 7;                         \
            const int gcol = (k0) + ((c8 ^ (row & 7)) * 8);                 \
            glds16(A  + (size_t)(m0 + row) * 1024 + gcol, &ldsA[buf][idx*8]);\
            glds16(Bt + (size_t)(n0 + row) * 1024 + gcol, &ldsB[buf][idx*8]);\
        }                                                                   \
    } while (0)

#define COMPUTE(buf)                                                        \
    do {                                                                    \
        _Pragma("unroll")                                                   \
        for (int kk = 0; kk < 2; kk++) {                                    \
            s8v af[2], bfr[2];                                              \
            _Pragma("unroll")                                               \
            for (int mf = 0; mf < 2; mf++)                                  \
                af[mf] = *(const s8v*)(&ldsA[buf][(wm*32+mf*16+c)*64 +      \
                                        (((kk<<2)+g) ^ (c&7)) * 8]);        \
            _Pragma("unroll")                                               \
            for (int nf = 0; nf < 2; nf++)                                  \
                bfr[nf] = *(const s8v*)(&ldsB[buf][(wn*32+nf*16+c)*64 +     \
                                        (((kk<<2)+g) ^ (c&7)) * 8]);        \
            _Pragma("unroll")                                               \
            for (int mf = 0; mf < 2; mf++)                                  \
                _Pragma("unroll")                                           \
                for (int nf = 0; nf < 2; nf++)                              \
                    acc[mf][nf] = mfma16(af[mf], bfr[nf], acc[mf][nf]);     \
        }                                                                   \
    } while (0)

    f4v acc[2][2];
    #pragma unroll
    for (int i = 0; i < 2; i++)
        #pragma unroll
        for (int j = 0; j < 2; j++) acc[i][j] = (f4v){0.f, 0.f, 0.f, 0.f};

    STAGEK(0, 0);
    STAGEK(1, 64);
    WAITBAR("4");
    int b0 = 0, b1 = 1, b2 = 2;
    for (int t = 0; t < 16; ++t) {
        if (t + 2 < 16) STAGEK(b2, (t + 2) * 64);
        COMPUTE(b0);
        if (t + 2 < 16)      WAITBAR("4");
        else if (t == 14)    WAITBAR("0");
        const int tmp = b0; b0 = b1; b1 = b2; b2 = tmp;
    }
#undef STAGEK
#undef COMPUTE

    gemm_epilogue<EPI>(acc, m0 + wm * 32, n0 + wn * 32, N, g, c,
                       bias, resio, outb, nullptr, nullptr, nullptr);
}

// ---------------- flash attention: 2-way K-SPLIT, 2-buffer, 128-kv phases ------
// blockIdx.z selects kv half [z*1024, z*1024+1024). Grid 1024 blocks -> 4/CU
// (LDS 32KB -> capacity 5/CU). Max-free softmax makes splits additive: each
// block writes PARTIAL f32 o and l; attn_merge normalizes. ATILE math is the
// R14-verified code (cvt_pk, permlane32_swap, ones-MFMA row sums).
__global__ __launch_bounds__(256) void attn_kernel(
        const short* __restrict__ qb, const short* __restrict__ kb,
        const short* __restrict__ vtb,
        float* __restrict__ po, float* __restrict__ pl) {
    __shared__ short ldsK[2][4096];   // [buf][2 tiles x 256 slots][8]
    __shared__ short ldsV[2][4096];
    const int bh = blockIdx.y;
    const int split = blockIdx.z;
    const int tid = threadIdx.x;
    const int wave = tid >> 6, lane = tid & 63;
    const int ql = lane & 31;       // q column this lane owns
    const int h2 = lane >> 5;       // lane half (contraction sub-block)
    const int q0 = blockIdx.x * 128 + wave * 32;
    const int klo = split * (SEQ / 2);
    const short* Q  = qb  + (size_t)bh * SEQ * HD;
    const short* Kp = kb  + (size_t)bh * SEQ * HD;
    const short* Vt = vtb + (size_t)bh * HD * SEQ;

    const s8v qf1 = *(const s8v*)(Q + (size_t)(q0 + ql) * HD + 8 * h2);
    const s8v qf2 = *(const s8v*)(Q + (size_t)(q0 + ql) * HD + 16 + 8 * h2);
    const s8v ones = (s8v){0x3F80,0x3F80,0x3F80,0x3F80,0x3F80,0x3F80,0x3F80,0x3F80};

    const f16v zero = {};
    f16v o   = zero;                // partial O^T[d][q]
    f16v lsv = zero;                // partial row sums

    const short* gK = Kp + (size_t)(tid & 63) * HD + (tid >> 6) * 8;
    const short* gV = Vt + (size_t)(tid & 31) * SEQ + (tid >> 5) * 8;

#define ASTAGE(buf, kt)                                                     \
    do {                                                                    \
        glds16(gK + (size_t)(kt) * HD,        &ldsK[buf][tid * 8]);         \
        glds16(gK + (size_t)((kt) + 64) * HD, &ldsK[buf][(256 + tid) * 8]); \
        glds16(gV + (kt),                     &ldsV[buf][tid * 8]);         \
        glds16(gV + (kt) + 64,                &ldsV[buf][(256 + tid) * 8]); \
    } while (0)

#define ATILE(buf, ti)                                                      \
    do {                                                                    \
        _Pragma("unroll")                                                   \
        for (int kk = 0; kk < 2; kk++) {                                    \
            const s8v ka1 = *(const s8v*)(&ldsK[buf][((ti)*256 + kk*32 + ql + 64*h2) * 8]);        \
            const s8v ka2 = *(const s8v*)(&ldsK[buf][((ti)*256 + kk*32 + ql + 128 + 64*h2) * 8]);  \
            f16v s_ = mfma32(ka1, qf1, zero);                               \
            s_ = mfma32(ka2, qf2, s_);                                      \
            float pr_[16];                                                  \
            _Pragma("unroll")                                               \
            for (int r = 0; r < 16; r++) pr_[r] = EXP2(s_[r]);              \
            int w_[8];                                                      \
            _Pragma("unroll")                                               \
            for (int i = 0; i < 8; i++)                                     \
                asm("v_cvt_pk_bf16_f32 %0, %1, %2"                          \
                    : "=v"(w_[i]) : "v"(pr_[2*i]), "v"(pr_[2*i+1]));        \
            asm("v_permlane32_swap_b32 %0, %1" : "+v"(w_[0]), "+v"(w_[2])); \
            asm("v_permlane32_swap_b32 %0, %1" : "+v"(w_[1]), "+v"(w_[3])); \
            asm("v_permlane32_swap_b32 %0, %1" : "+v"(w_[4]), "+v"(w_[6])); \
            asm("v_permlane32_swap_b32 %0, %1" : "+v"(w_[5]), "+v"(w_[7])); \
            union { int i[4]; s8v v; } B1_, B2_;                            \
            B1_.i[0]=w_[0]; B1_.i[1]=w_[1]; B1_.i[2]=w_[2]; B1_.i[3]=w_[3]; \
            B2_.i[0]=w_[4]; B2_.i[1]=w_[5]; B2_.i[2]=w_[6]; B2_.i[3]=w_[7]; \
            lsv = mfma32(ones, B1_.v, lsv);                                 \
            lsv = mfma32(ones, B2_.v, lsv);                                 \
            const s8v va1 = *(const s8v*)(&ldsV[buf][((ti)*256 + ql + 128*kk + 32*h2) * 8]);       \
            const s8v va2 = *(const s8v*)(&ldsV[buf][((ti)*256 + ql + 128*kk + 64 + 32*h2) * 8]);  \
            o = mfma32(va1, B1_.v, o);                                      \
            o = mfma32(va2, B2_.v, o);                                      \
        }                                                                   \
    } while (0)

    ASTAGE(0, klo);
    WAITBAR("0");
    #pragma unroll
    for (int ph = 0; ph < 8; ++ph) {
        if (ph + 1 < 8) ASTAGE((ph + 1) & 1, klo + (ph + 1) * 128);
        ATILE(ph & 1, 0);
        ATILE(ph & 1, 1);
        if (ph + 1 < 8) WAITBAR("0");   // stage issued a full compute-phase ago
    }
#undef ASTAGE
#undef ATILE

    // partial epilogue: lane (ql,h2) holds o[r] for d=(r&3)+8*(r>>2)+4*h2, q=ql
    float* pob = po + (((size_t)split * 32 + bh) * SEQ + q0 + ql) * HD;
    #pragma unroll
    for (int rr = 0; rr < 4; rr++) {
        const f4v pv = (f4v){o[4*rr], o[4*rr+1], o[4*rr+2], o[4*rr+3]};
        *(f4v*)(pob + 8 * rr + 4 * h2) = pv;
    }
    if (lane < 32) pl[((size_t)split * 32 + bh) * SEQ + q0 + ql] = lsv[0];
}

// ---------------- attn merge: (o0+o1)/(l0+l1) -> bf16 ao ----------------
__global__ __launch_bounds__(256) void attn_merge(
        const float* __restrict__ po, const float* __restrict__ pl,
        short* __restrict__ ao) {
    const int t = threadIdx.x;
    const int q = blockIdx.x * 8 + (t >> 5);
    const int d = t & 31;
    const int bh = blockIdx.y, b = bh >> 3, h = bh & 7;
    const size_t i0 = ((size_t)bh * SEQ + q) * HD + d;
    const size_t i1 = ((size_t)(32 + bh) * SEQ + q) * HD + d;
    const float ov = po[i0] + po[i1];
    const float l  = pl[(size_t)bh * SEQ + q] + pl[(size_t)(32 + bh) * SEQ + q];
    ao[((size_t)(b * SEQ + q)) * DMODEL + h * HD + d] = f2bf(ov / l);
}

// -------------------------------- launcher --------------------------------
extern "C" void kernel_launch(void* const* d_in, const int* in_sizes, int n_in,
                              void* d_out, int out_size, void* d_ws, size_t ws_size,
                              hipStream_t stream) {
    const float* w_qkv = (const float*)d_in[3];
    const float* w_out = (const float*)d_in[4];
    const float* b_out = (const float*)d_in[5];
    const float* w1    = (const float*)d_in[8];
    const float* b1    = (const float*)d_in[9];
    const float* w2    = (const float*)d_in[10];
    const float* b2    = (const float*)d_in[11];
    const float* ln1_g = (const float*)d_in[1];
    const float* ln1_b = (const float*)d_in[2];
    const float* ln2_g = (const float*)d_in[6];
    const float* ln2_b = (const float*)d_in[7];
    float* xout = (float*)d_out;

    short* ws    = (short*)d_ws;
    short* xn    = ws;
    short* qb    = xn    + (size_t)NTOK * DMODEL;
    short* kb    = qb    + (size_t)BATCH * NH * SEQ * HD;
    short* vtb   = kb    + (size_t)BATCH * NH * SEQ * HD;
    short* ao    = vtb   + (size_t)BATCH * NH * SEQ * HD;
    short* mid   = ao    + (size_t)NTOK * DMODEL;
    short* wqkvT = mid   + (size_t)NTOK * MLPD;
    short* woutT = wqkvT + (size_t)DEPTH * 3 * DMODEL * DMODEL;
    short* w1T   = woutT + (size_t)DEPTH * DMODEL * DMODEL;
    short* w2T   = w1T   + (size_t)DEPTH * MLPD * DMODEL;
    float* po    = (float*)(w2T + (size_t)DEPTH * DMODEL * MLPD);   // 2*32*SEQ*HD f32
    float* pl    = po + (size_t)2 * 32 * SEQ * HD;                  // 2*32*SEQ f32

    hipMemcpyAsync(d_out, d_in[0], (size_t)NTOK * DMODEL * sizeof(float),
                   hipMemcpyDeviceToDevice, stream);

    transpose_cvt<<<dim3(3*DMODEL/32, DMODEL/32, DEPTH), dim3(32, 8), 0, stream>>>(
        w_qkv, wqkvT, DMODEL, 3*DMODEL);
    transpose_cvt<<<dim3(DMODEL/32, DMODEL/32, DEPTH), dim3(32, 8), 0, stream>>>(
        w_out, woutT, DMODEL, DMODEL);
    transpose_cvt<<<dim3(MLPD/32, DMODEL/32, DEPTH), dim3(32, 8), 0, stream>>>(
        w1, w1T, DMODEL, MLPD);
    transpose_cvt<<<dim3(DMODEL/32, MLPD/32, DEPTH), dim3(32, 8), 0, stream>>>(
        w2, w2T, MLPD, DMODEL);

    for (int l = 0; l < DEPTH; l++) {
        ln_kernel<<<NTOK/4, 256, 0, stream>>>(xout, ln1_g + l*DMODEL, ln1_b + l*DMODEL, xn);
        gemm_p256<EPI_QKV><<<1536, 256, 0, stream>>>(
            xn, wqkvT + (size_t)l * 3 * DMODEL * DMODEL,
            3*DMODEL, 12, nullptr, nullptr, nullptr, qb, kb, vtb);
        attn_kernel<<<dim3(SEQ/128, BATCH*NH, 2), 256, 0, stream>>>(qb, kb, vtb, po, pl);
        attn_merge<<<dim3(SEQ/8, BATCH*NH), 256, 0, stream>>>(po, pl, ao);
        gemm_p256<EPI_RES><<<512, 256, 0, stream>>>(
            ao, woutT + (size_t)l * DMODEL * DMODEL,
            DMODEL, 4, b_out + l*DMODEL, xout, nullptr, nullptr, nullptr, nullptr);
        ln_kernel<<<NTOK/4, 256, 0, stream>>>(xout, ln2_g + l*DMODEL, ln2_b + l*DMODEL, xn);
        gemm_p256<EPI_GELU><<<2048, 256, 0, stream>>>(
            xn, w1T + (size_t)l * MLPD * DMODEL,
            MLPD, 16, b1 + l*MLPD, nullptr, mid, nullptr, nullptr, nullptr);
        gemm_p1024<EPI_RES><<<512, 256, 0, stream>>>(
            mid, w2T + (size_t)l * DMODEL * MLPD,
            DMODEL, 4, b2 + l*DMODEL, xout, nullptr);
    }
}

// Round 17
// 359.788 us; speedup vs baseline: 1.0696x; 1.0696x over previous
//
#include <hip/hip_runtime.h>
#include <hip/hip_bf16.h>

#define DEPTH  4
#define NH     8
#define DMODEL 256
#define HD     32
#define MLPD   1024
#define SEQ    2048
#define BATCH  4
#define NTOK   (BATCH*SEQ)

typedef __attribute__((ext_vector_type(8))) short s8v;   // 8 bf16 (MFMA A/B frag)
typedef __attribute__((ext_vector_type(4))) short s4v;
typedef __attribute__((ext_vector_type(4))) float f4v;   // 16x16 MFMA C/D frag
typedef __attribute__((ext_vector_type(16))) float f16v; // 32x32 MFMA C/D frag

#if __has_builtin(__builtin_amdgcn_exp2f)
#define EXP2(x) __builtin_amdgcn_exp2f(x)
#else
#define EXP2(x) exp2f(x)
#endif

__device__ __forceinline__ short f2bf(float f) {
    union { float f; unsigned u; } v; v.f = f;
    unsigned r = v.u + 0x7fffu + ((v.u >> 16) & 1u);   // RNE
    return (short)(r >> 16);
}

__device__ __forceinline__ f4v mfma16(s8v a, s8v b, f4v c) {
    return __builtin_amdgcn_mfma_f32_16x16x32_bf16(a, b, c, 0, 0, 0);
}
__device__ __forceinline__ f16v mfma32(s8v a, s8v b, f16v c) {
    return __builtin_amdgcn_mfma_f32_32x32x16_bf16(a, b, c, 0, 0, 0);
}

__device__ __forceinline__ void glds16(const short* g, short* l) {
    __builtin_amdgcn_global_load_lds(
        (const __attribute__((address_space(1))) void*)g,
        (__attribute__((address_space(3))) void*)l, 16, 0, 0);
}

// counted-vmcnt barrier: do NOT drain the in-flight prefetch (T4).
#define WAITBAR(NLIT)                                                       \
    do {                                                                    \
        __builtin_amdgcn_sched_barrier(0);                                  \
        asm volatile("s_waitcnt vmcnt(" NLIT ")" ::: "memory");             \
        __builtin_amdgcn_s_barrier();                                       \
        __builtin_amdgcn_sched_barrier(0);                                  \
    } while (0)

// ---------------- weight transpose + f32->bf16 ----------------
__global__ void transpose_cvt(const float* __restrict__ src, short* __restrict__ dst,
                              int K, int N) {
    __shared__ float tile[32][33];
    const int l = blockIdx.z;
    src += (size_t)l * K * N;
    dst += (size_t)l * N * K;
    const int n0 = blockIdx.x * 32, k0 = blockIdx.y * 32;
    const int tx = threadIdx.x, ty = threadIdx.y;   // 32 x 8
    #pragma unroll
    for (int i = 0; i < 32; i += 8)
        tile[ty + i][tx] = src[(size_t)(k0 + ty + i) * N + n0 + tx];
    __syncthreads();
    #pragma unroll
    for (int i = 0; i < 32; i += 8)
        dst[(size_t)(n0 + ty + i) * K + k0 + tx] = f2bf(tile[tx][ty + i]);
}

// ---------------- LayerNorm: x f32 [NTOK][256] -> bf16 ----------------
__global__ void ln_kernel(const float* __restrict__ x, const float* __restrict__ g,
                          const float* __restrict__ b, short* __restrict__ out) {
    const int row  = blockIdx.x * 4 + (threadIdx.x >> 6);
    const int lane = threadIdx.x & 63;
    const float4 v = *(const float4*)(x + (size_t)row * DMODEL + lane * 4);
    float s = v.x + v.y + v.z + v.w;
    #pragma unroll
    for (int m = 32; m; m >>= 1) s += __shfl_xor(s, m);
    const float mean = s * (1.0f / DMODEL);
    const float dx = v.x - mean, dy = v.y - mean, dz = v.z - mean, dw = v.w - mean;
    float q = dx*dx + dy*dy + dz*dz + dw*dw;
    #pragma unroll
    for (int m = 32; m; m >>= 1) q += __shfl_xor(q, m);
    const float rstd = rsqrtf(q * (1.0f / DMODEL) + 1e-5f);
    const float4 gg = *(const float4*)(g + lane * 4);
    const float4 bb = *(const float4*)(b + lane * 4);
    s4v o;
    o.x = f2bf(dx * rstd * gg.x + bb.x);
    o.y = f2bf(dy * rstd * gg.y + bb.y);
    o.z = f2bf(dz * rstd * gg.z + bb.z);
    o.w = f2bf(dw * rstd * gg.w + bb.w);
    *(s4v*)(out + (size_t)row * DMODEL + lane * 4) = o;
}

#define EPI_QKV  0
#define EPI_RES  1
#define EPI_GELU 2

// -------- generic epilogue (R12-validated for FM/FN in {2,4}) --------
template<int FM, int FN, int EPI>
__device__ __forceinline__ void gemm_epilogue(
        f4v acc[FM][FN], int trow0, int col0, int N, int g, int c,
        const float* __restrict__ bias, float* __restrict__ resio,
        short* __restrict__ outb,
        short* __restrict__ qb, short* __restrict__ kb, short* __restrict__ vtb) {
    if (EPI == EPI_QKV) {
        #pragma unroll
        for (int mf = 0; mf < FM; mf++) {
            const int tokb = trow0 + mf * 16 + g * 4;
            const int b = tokb >> 11, n = tokb & 2047;
            #pragma unroll
            for (int nf = 0; nf < FN; nf++) {
                const int colg = col0 + nf * 16 + c;
                const int part = colg >> 8, pc = colg & 255;
                const int h = pc >> 5, d = pc & 31;
                const size_t bh = (size_t)(b * NH + h);
                if (part == 2) {
                    s4v pv;
                    #pragma unroll
                    for (int r = 0; r < 4; r++) pv[r] = f2bf(acc[mf][nf][r]);
                    *(s4v*)(vtb + (bh * 32 + d) * SEQ + n) = pv;
                } else {
                    // q pre-scaled by dim^-0.5 * log2(e) so attention can exp2 raw scores
                    const float sc = (part == 0) ? 0.090168440f : 1.0f;
                    short* dst = (part == 0 ? qb : kb) + ((bh << 11) + n) * 32 + d;
                    #pragma unroll
                    for (int r = 0; r < 4; r++) dst[(size_t)r * 32] = f2bf(acc[mf][nf][r] * sc);
                }
            }
        }
    } else if (EPI == EPI_RES) {
        #pragma unroll
        for (int mf = 0; mf < FM; mf++)
            #pragma unroll
            for (int nf = 0; nf < FN; nf++) {
                const int colg = col0 + nf * 16 + c;
                const float bv = bias[colg];
                #pragma unroll
                for (int r = 0; r < 4; r++) {
                    const int row = trow0 + mf * 16 + g * 4 + r;
                    const size_t idx = (size_t)row * N + colg;
                    resio[idx] = resio[idx] + bv + acc[mf][nf][r];
                }
            }
    } else {  // EPI_GELU
        #pragma unroll
        for (int mf = 0; mf < FM; mf++)
            #pragma unroll
            for (int nf = 0; nf < FN; nf++) {
                const int colg = col0 + nf * 16 + c;
                const float bv = bias[colg];
                #pragma unroll
                for (int r = 0; r < 4; r++) {
                    const int row = trow0 + mf * 16 + g * 4 + r;
                    const float v = acc[mf][nf][r] + bv;
                    const float ge = 0.5f * v * (1.0f + erff(v * 0.70710678118f));
                    outb[(size_t)row * N + colg] = f2bf(ge);
                }
            }
    }
}

// ---------------- K=256 GEMM, 64x64 tile: 3-buffer counted-vmcnt (R8-verified) --
template<int EPI>
__global__ __launch_bounds__(256) void gemm_p256(
        const short* __restrict__ A, const short* __restrict__ Bt,
        const int N, const int nbx,
        const float* __restrict__ bias,
        float* __restrict__ resio,
        short* __restrict__ outb,
        short* __restrict__ qb, short* __restrict__ kb, short* __restrict__ vtb) {
    __shared__ short ldsA[3][64 * 64];
    __shared__ short ldsB[3][64 * 64];
    const int nblk = gridDim.x;
    const int bid  = blockIdx.x;
    const int swz  = (bid & 7) * (nblk >> 3) + (bid >> 3);   // XCD-chunked
    const int m0 = (swz / nbx) * 64, n0 = (swz % nbx) * 64;
    const int tid  = threadIdx.x;
    const int wave = tid >> 6, lane = tid & 63;
    const int g = lane >> 4, c = lane & 15;
    const int wm = wave >> 1, wn = wave & 1;

#define STAGEP(buf, k0)                                                     \
    do {                                                                    \
        _Pragma("unroll")                                                   \
        for (int i = 0; i < 2; i++) {                                       \
            const int idx = i * 256 + tid;                                  \
            const int row = idx >> 3, c8 = idx & 7;                         \
            const int gcol = (k0) + ((c8 ^ (row & 7)) * 8);                 \
            glds16(A  + (size_t)(m0 + row) * 256 + gcol, &ldsA[buf][idx*8]);\
            glds16(Bt + (size_t)(n0 + row) * 256 + gcol, &ldsB[buf][idx*8]);\
        }                                                                   \
    } while (0)

#define COMPUTE(buf)                                                        \
    do {                                                                    \
        _Pragma("unroll")                                                   \
        for (int kk = 0; kk < 2; kk++) {                                    \
            s8v af[2], bfr[2];                                              \
            _Pragma("unroll")                                               \
            for (int mf = 0; mf < 2; mf++)                                  \
                af[mf] = *(const s8v*)(&ldsA[buf][(wm*32+mf*16+c)*64 +      \
                                        (((kk<<2)+g) ^ (c&7)) * 8]);        \
            _Pragma("unroll")                                               \
            for (int nf = 0; nf < 2; nf++)                                  \
                bfr[nf] = *(const s8v*)(&ldsB[buf][(wn*32+nf*16+c)*64 +     \
                                        (((kk<<2)+g) ^ (c&7)) * 8]);        \
            _Pragma("unroll")                                               \
            for (int mf = 0; mf < 2; mf++)                                  \
                _Pragma("unroll")                                           \
                for (int nf = 0; nf < 2; nf++)                              \
                    acc[mf][nf] = mfma16(af[mf], bfr[nf], acc[mf][nf]);     \
        }                                                                   \
    } while (0)

    f4v acc[2][2];
    #pragma unroll
    for (int i = 0; i < 2; i++)
        #pragma unroll
        for (int j = 0; j < 2; j++) acc[i][j] = (f4v){0.f, 0.f, 0.f, 0.f};

    STAGEP(0, 0);
    STAGEP(1, 64);
    WAITBAR("4");
    STAGEP(2, 128);
    COMPUTE(0);
    WAITBAR("4");
    STAGEP(0, 192);
    COMPUTE(1);
    WAITBAR("4");
    COMPUTE(2);
    WAITBAR("0");
    COMPUTE(0);
#undef STAGEP
#undef COMPUTE

    gemm_epilogue<2, 2, EPI>(acc, m0 + wm * 32, n0 + wn * 32, N, g, c,
                             bias, resio, outb, qb, kb, vtb);
}

// ---------------- K=256 GEMM, 64x128 tile (QKV/FFN1): same counted schedule ----
// FM=2, FN=4; per wave 32x64 region. LDS 72KB -> 2 blocks/CU. 6 loads/thread
// per stage -> WAITBAR("6"). Schedule/invariants identical to gemm_p256.
template<int EPI>
__global__ __launch_bounds__(256) void gemm_pw(
        const short* __restrict__ A, const short* __restrict__ Bt,
        const int N, const int nbx,
        const float* __restrict__ bias,
        float* __restrict__ resio,
        short* __restrict__ outb,
        short* __restrict__ qb, short* __restrict__ kb, short* __restrict__ vtb) {
    __shared__ short ldsA[3][64 * 64];
    __shared__ short ldsB[3][128 * 64];
    const int nblk = gridDim.x;
    const int bid  = blockIdx.x;
    const int swz  = (bid & 7) * (nblk >> 3) + (bid >> 3);   // XCD-chunked
    const int m0 = (swz / nbx) * 64, n0 = (swz % nbx) * 128;
    const int tid  = threadIdx.x;
    const int wave = tid >> 6, lane = tid & 63;
    const int g = lane >> 4, c = lane & 15;
    const int wm = wave >> 1, wn = wave & 1;

#define STAGEW(buf, k0)                                                     \
    do {                                                                    \
        _Pragma("unroll")                                                   \
        for (int i = 0; i < 2; i++) {                                       \
            const int idx = i * 256 + tid;                                  \
            const int row = idx >> 3, c8 = idx & 7;                         \
            const int gcol = (k0) + ((c8 ^ (row & 7)) * 8);                 \
            glds16(A + (size_t)(m0 + row) * 256 + gcol, &ldsA[buf][idx*8]); \
        }                                                                   \
        _Pragma("unroll")                                                   \
        for (int i = 0; i < 4; i++) {                                       \
            const int idx = i * 256 + tid;                                  \
            const int row = idx >> 3, c8 = idx & 7;                         \
            const int gcol = (k0) + ((c8 ^ (row & 7)) * 8);                 \
            glds16(Bt + (size_t)(n0 + row) * 256 + gcol, &ldsB[buf][idx*8]);\
        }                                                                   \
    } while (0)

#define COMPUTEW(buf)                                                       \
    do {                                                                    \
        _Pragma("unroll")                                                   \
        for (int kk = 0; kk < 2; kk++) {                                    \
            s8v af[2], bfr[4];                                              \
            _Pragma("unroll")                                               \
            for (int mf = 0; mf < 2; mf++)                                  \
                af[mf] = *(const s8v*)(&ldsA[buf][(wm*32+mf*16+c)*64 +      \
                                        (((kk<<2)+g) ^ (c&7)) * 8]);        \
            _Pragma("unroll")                                               \
            for (int nf = 0; nf < 4; nf++)                                  \
                bfr[nf] = *(const s8v*)(&ldsB[buf][(wn*64+nf*16+c)*64 +     \
                                        (((kk<<2)+g) ^ (c&7)) * 8]);        \
            _Pragma("unroll")                                               \
            for (int mf = 0; mf < 2; mf++)                                  \
                _Pragma("unroll")                                           \
                for (int nf = 0; nf < 4; nf++)                              \
                    acc[mf][nf] = mfma16(af[mf], bfr[nf], acc[mf][nf]);     \
        }                                                                   \
    } while (0)

    f4v acc[2][4];
    #pragma unroll
    for (int i = 0; i < 2; i++)
        #pragma unroll
        for (int j = 0; j < 4; j++) acc[i][j] = (f4v){0.f, 0.f, 0.f, 0.f};

    STAGEW(0, 0);
    STAGEW(1, 64);
    WAITBAR("6");
    STAGEW(2, 128);
    COMPUTEW(0);
    WAITBAR("6");
    STAGEW(0, 192);
    COMPUTEW(1);
    WAITBAR("6");
    COMPUTEW(2);
    WAITBAR("0");
    COMPUTEW(0);
#undef STAGEW
#undef COMPUTEW

    gemm_epilogue<2, 4, EPI>(acc, m0 + wm * 32, n0 + wn * 64, N, g, c,
                             bias, resio, outb, qb, kb, vtb);
}

// ---------------- K=1024 GEMM (FFN2): rolling 3-buffer counted-vmcnt ----------
template<int EPI>
__global__ __launch_bounds__(256) void gemm_p1024(
        const short* __restrict__ A, const short* __restrict__ Bt,
        const int N, const int nbx,
        const float* __restrict__ bias,
        float* __restrict__ resio,
        short* __restrict__ outb) {
    __shared__ short ldsA[3][64 * 64];
    __shared__ short ldsB[3][64 * 64];
    const int nblk = gridDim.x;
    const int bid  = blockIdx.x;
    const int swz  = (bid & 7) * (nblk >> 3) + (bid >> 3);
    const int m0 = (swz / nbx) * 64, n0 = (swz % nbx) * 64;
    const int tid  = threadIdx.x;
    const int wave = tid >> 6, lane = tid & 63;
    const int g = lane >> 4, c = lane & 15;
    const int wm = wave >> 1, wn = wave & 1;

#define STAGEK(buf, k0)                                                     \
    do {                                                                    \
        _Pragma("unroll")                                                   \
        for (int i = 0; i < 2; i++) {                                       \
            const int idx = i * 256 + tid;                                  \
            const int row = idx >> 3, c8 = idx & 7;                         \
            const int gcol = (k0) + ((c8 ^ (row & 7)) * 8);                 \
            glds16(A  + (size_t)(m0 + row) * 1024 + gcol, &ldsA[buf][idx*8]);\
            glds16(Bt + (size_t)(n0 + row) * 1024 + gcol, &ldsB[buf][idx*8]);\
        }                                                                   \
    } while (0)

#define COMPUTE(buf)                                                        \
    do {                                                                    \
        _Pragma("unroll")                                                   \
        for (int kk = 0; kk < 2; kk++) {                                    \
            s8v af[2], bfr[2];                                              \
            _Pragma("unroll")                                               \
            for (int mf = 0; mf < 2; mf++)                                  \
                af[mf] = *(const s8v*)(&ldsA[buf][(wm*32+mf*16+c)*64 +      \
                                        (((kk<<2)+g) ^ (c&7)) * 8]);        \
            _Pragma("unroll")                                               \
            for (int nf = 0; nf < 2; nf++)                                  \
                bfr[nf] = *(const s8v*)(&ldsB[buf][(wn*32+nf*16+c)*64 +     \
                                        (((kk<<2)+g) ^ (c&7)) * 8]);        \
            _Pragma("unroll")                                               \
            for (int mf = 0; mf < 2; mf++)                                  \
                _Pragma("unroll")                                           \
                for (int nf = 0; nf < 2; nf++)                              \
                    acc[mf][nf] = mfma16(af[mf], bfr[nf], acc[mf][nf]);     \
        }                                                                   \
    } while (0)

    f4v acc[2][2];
    #pragma unroll
    for (int i = 0; i < 2; i++)
        #pragma unroll
        for (int j = 0; j < 2; j++) acc[i][j] = (f4v){0.f, 0.f, 0.f, 0.f};

    STAGEK(0, 0);
    STAGEK(1, 64);
    WAITBAR("4");
    int b0 = 0, b1 = 1, b2 = 2;
    for (int t = 0; t < 16; ++t) {
        if (t + 2 < 16) STAGEK(b2, (t + 2) * 64);
        COMPUTE(b0);
        if (t + 2 < 16)      WAITBAR("4");
        else if (t == 14)    WAITBAR("0");
        const int tmp = b0; b0 = b1; b1 = b2; b2 = tmp;
    }
#undef STAGEK
#undef COMPUTE

    gemm_epilogue<2, 2, EPI>(acc, m0 + wm * 32, n0 + wn * 32, N, g, c,
                             bias, resio, outb, nullptr, nullptr, nullptr);
}

// ---------------- flash attention: R14 version (best known, ~37us) ----------------
// 4 waves x 32q, shared K/V in LDS, 3-buffer counted-vmcnt, 128-kv phases,
// hardware cvt_pk packing, fully unrolled. Max-free softmax, in-register P^T,
// ones-MFMA row sums.
__global__ __launch_bounds__(256) void attn_kernel(
        const short* __restrict__ qb, const short* __restrict__ kb,
        const short* __restrict__ vtb, short* __restrict__ out) {
    __shared__ short ldsK[3][4096];   // [buf][2 tiles x 256 slots][8]
    __shared__ short ldsV[3][4096];
    const int bh = blockIdx.y;
    const int tid = threadIdx.x;
    const int wave = tid >> 6, lane = tid & 63;
    const int ql = lane & 31;       // q column this lane owns
    const int h2 = lane >> 5;       // lane half (contraction sub-block)
    const int q0 = blockIdx.x * 128 + wave * 32;
    const short* Q  = qb  + (size_t)bh * SEQ * HD;
    const short* Kp = kb  + (size_t)bh * SEQ * HD;
    const short* Vt = vtb + (size_t)bh * HD * SEQ;

    const s8v qf1 = *(const s8v*)(Q + (size_t)(q0 + ql) * HD + 8 * h2);
    const s8v qf2 = *(const s8v*)(Q + (size_t)(q0 + ql) * HD + 16 + 8 * h2);
    const s8v ones = (s8v){0x3F80,0x3F80,0x3F80,0x3F80,0x3F80,0x3F80,0x3F80,0x3F80};

    const f16v zero = {};
    f16v o   = zero;                // O^T[d][q] accumulator
    f16v lsv = zero;                // every reg = running sum_k P[k][q]

    const short* gK = Kp + (size_t)(tid & 63) * HD + (tid >> 6) * 8;
    const short* gV = Vt + (size_t)(tid & 31) * SEQ + (tid >> 5) * 8;

#define ASTAGE(buf, kt)                                                     \
    do {                                                                    \
        glds16(gK + (size_t)(kt) * HD,        &ldsK[buf][tid * 8]);         \
        glds16(gK + (size_t)((kt) + 64) * HD, &ldsK[buf][(256 + tid) * 8]); \
        glds16(gV + (kt),                     &ldsV[buf][tid * 8]);         \
        glds16(gV + (kt) + 64,                &ldsV[buf][(256 + tid) * 8]); \
    } while (0)

#define ATILE(buf, ti)                                                      \
    do {                                                                    \
        _Pragma("unroll")                                                   \
        for (int kk = 0; kk < 2; kk++) {                                    \
            const s8v ka1 = *(const s8v*)(&ldsK[buf][((ti)*256 + kk*32 + ql + 64*h2) * 8]);        \
            const s8v ka2 = *(const s8v*)(&ldsK[buf][((ti)*256 + kk*32 + ql + 128 + 64*h2) * 8]);  \
            f16v s_ = mfma32(ka1, qf1, zero);                               \
            s_ = mfma32(ka2, qf2, s_);                                      \
            float pr_[16];                                                  \
            _Pragma("unroll")                                               \
            for (int r = 0; r < 16; r++) pr_[r] = EXP2(s_[r]);              \
            int w_[8];                                                      \
            _Pragma("unroll")                                               \
            for (int i = 0; i < 8; i++)                                     \
                asm("v_cvt_pk_bf16_f32 %0, %1, %2"                          \
                    : "=v"(w_[i]) : "v"(pr_[2*i]), "v"(pr_[2*i+1]));        \
            asm("v_permlane32_swap_b32 %0, %1" : "+v"(w_[0]), "+v"(w_[2])); \
            asm("v_permlane32_swap_b32 %0, %1" : "+v"(w_[1]), "+v"(w_[3])); \
            asm("v_permlane32_swap_b32 %0, %1" : "+v"(w_[4]), "+v"(w_[6])); \
            asm("v_permlane32_swap_b32 %0, %1" : "+v"(w_[5]), "+v"(w_[7])); \
            union { int i[4]; s8v v; } B1_, B2_;                            \
            B1_.i[0]=w_[0]; B1_.i[1]=w_[1]; B1_.i[2]=w_[2]; B1_.i[3]=w_[3]; \
            B2_.i[0]=w_[4]; B2_.i[1]=w_[5]; B2_.i[2]=w_[6]; B2_.i[3]=w_[7]; \
            lsv = mfma32(ones, B1_.v, lsv);                                 \
            lsv = mfma32(ones, B2_.v, lsv);                                 \
            const s8v va1 = *(const s8v*)(&ldsV[buf][((ti)*256 + ql + 128*kk + 32*h2) * 8]);       \
            const s8v va2 = *(const s8v*)(&ldsV[buf][((ti)*256 + ql + 128*kk + 64 + 32*h2) * 8]);  \
            o = mfma32(va1, B1_.v, o);                                      \
            o = mfma32(va2, B2_.v, o);                                      \
        }                                                                   \
    } while (0)

    ASTAGE(0, 0);
    ASTAGE(1, 128);
    WAITBAR("4");                       // phase 0 landed; phase 1 in flight
    #pragma unroll
    for (int ph = 0; ph < 16; ++ph) {
        const int cbuf = ph % 3;
        const int nbuf = (ph + 2) % 3;
        if (ph + 2 < 16) ASTAGE(nbuf, (ph + 2) * 128);
        ATILE(cbuf, 0);
        ATILE(cbuf, 1);
        if (ph + 2 < 16)      WAITBAR("4");   // phase ph+1 landed, ph+2 in flight
        else if (ph == 14)    WAITBAR("0");   // last phase landed
    }
#undef ASTAGE
#undef ATILE

    // direct epilogue: lane (ql,h2) holds o[r] for d=(r&3)+8*(r>>2)+4*h2, q=ql
    const int b = bh >> 3, hh = bh & 7;
    const float inv = 1.0f / lsv[0];
    const size_t rowoff = (size_t)(b * SEQ + q0 + ql) * DMODEL + hh * HD;
    #pragma unroll
    for (int rr = 0; rr < 4; rr++) {
        union { int i[2]; s4v v; } uo;
        const float e0 = o[4*rr]   * inv, e1 = o[4*rr+1] * inv;
        const float e2 = o[4*rr+2] * inv, e3 = o[4*rr+3] * inv;
        asm("v_cvt_pk_bf16_f32 %0, %1, %2" : "=v"(uo.i[0]) : "v"(e0), "v"(e1));
        asm("v_cvt_pk_bf16_f32 %0, %1, %2" : "=v"(uo.i[1]) : "v"(e2), "v"(e3));
        *(s4v*)(out + rowoff + 8 * rr + 4 * h2) = uo.v;
    }
}

// -------------------------------- launcher --------------------------------
extern "C" void kernel_launch(void* const* d_in, const int* in_sizes, int n_in,
                              void* d_out, int out_size, void* d_ws, size_t ws_size,
                              hipStream_t stream) {
    const float* w_qkv = (const float*)d_in[3];
    const float* w_out = (const float*)d_in[4];
    const float* b_out = (const float*)d_in[5];
    const float* w1    = (const float*)d_in[8];
    const float* b1    = (const float*)d_in[9];
    const float* w2    = (const float*)d_in[10];
    const float* b2    = (const float*)d_in[11];
    const float* ln1_g = (const float*)d_in[1];
    const float* ln1_b = (const float*)d_in[2];
    const float* ln2_g = (const float*)d_in[6];
    const float* ln2_b = (const float*)d_in[7];
    float* xout = (float*)d_out;

    short* ws    = (short*)d_ws;
    short* xn    = ws;
    short* qb    = xn    + (size_t)NTOK * DMODEL;
    short* kb    = qb    + (size_t)BATCH * NH * SEQ * HD;
    short* vtb   = kb    + (size_t)BATCH * NH * SEQ * HD;
    short* ao    = vtb   + (size_t)BATCH * NH * SEQ * HD;
    short* mid   = ao    + (size_t)NTOK * DMODEL;
    short* wqkvT = mid   + (size_t)NTOK * MLPD;
    short* woutT = wqkvT + (size_t)DEPTH * 3 * DMODEL * DMODEL;
    short* w1T   = woutT + (size_t)DEPTH * DMODEL * DMODEL;
    short* w2T   = w1T   + (size_t)DEPTH * MLPD * DMODEL;

    hipMemcpyAsync(d_out, d_in[0], (size_t)NTOK * DMODEL * sizeof(float),
                   hipMemcpyDeviceToDevice, stream);

    transpose_cvt<<<dim3(3*DMODEL/32, DMODEL/32, DEPTH), dim3(32, 8), 0, stream>>>(
        w_qkv, wqkvT, DMODEL, 3*DMODEL);
    transpose_cvt<<<dim3(DMODEL/32, DMODEL/32, DEPTH), dim3(32, 8), 0, stream>>>(
        w_out, woutT, DMODEL, DMODEL);
    transpose_cvt<<<dim3(MLPD/32, DMODEL/32, DEPTH), dim3(32, 8), 0, stream>>>(
        w1, w1T, DMODEL, MLPD);
    transpose_cvt<<<dim3(DMODEL/32, MLPD/32, DEPTH), dim3(32, 8), 0, stream>>>(
        w2, w2T, MLPD, DMODEL);

    for (int l = 0; l < DEPTH; l++) {
        ln_kernel<<<NTOK/4, 256, 0, stream>>>(xout, ln1_g + l*DMODEL, ln1_b + l*DMODEL, xn);
        gemm_pw<EPI_QKV><<<768, 256, 0, stream>>>(
            xn, wqkvT + (size_t)l * 3 * DMODEL * DMODEL,
            3*DMODEL, 6, nullptr, nullptr, nullptr, qb, kb, vtb);
        attn_kernel<<<dim3(SEQ/128, BATCH*NH), 256, 0, stream>>>(qb, kb, vtb, ao);
        gemm_p256<EPI_RES><<<512, 256, 0, stream>>>(
            ao, woutT + (size_t)l * DMODEL * DMODEL,
            DMODEL, 4, b_out + l*DMODEL, xout, nullptr, nullptr, nullptr, nullptr);
        ln_kernel<<<NTOK/4, 256, 0, stream>>>(xout, ln2_g + l*DMODEL, ln2_b + l*DMODEL, xn);
        gemm_pw<EPI_GELU><<<1024, 256, 0, stream>>>(
            xn, w1T + (size_t)l * MLPD * DMODEL,
            MLPD, 8, b1 + l*MLPD, nullptr, mid, nullptr, nullptr, nullptr);
        gemm_p1024<EPI_RES><<<512, 256, 0, stream>>>(
            mid, w2T + (size_t)l * DMODEL * MLPD,
            DMODEL, 4, b2 + l*DMODEL, xout, nullptr);
    }
}

// Round 18
// 341.227 us; speedup vs baseline: 1.1278x; 1.0544x over previous
//
#include <hip/hip_runtime.h>
#include <hip/hip_bf16.h>

#define DEPTH  4
#define NH     8
#define DMODEL 256
#define HD     32
#define MLPD   1024
#define SEQ    2048
#define BATCH  4
#define NTOK   (BATCH*SEQ)

typedef __attribute__((ext_vector_type(8))) short s8v;   // 8 bf16 (MFMA A/B frag)
typedef __attribute__((ext_vector_type(4))) short s4v;
typedef __attribute__((ext_vector_type(4))) float f4v;   // 16x16 MFMA C/D frag
typedef __attribute__((ext_vector_type(16))) float f16v; // 32x32 MFMA C/D frag

#if __has_builtin(__builtin_amdgcn_exp2f)
#define EXP2(x) __builtin_amdgcn_exp2f(x)
#else
#define EXP2(x) exp2f(x)
#endif

__device__ __forceinline__ short f2bf(float f) {
    union { float f; unsigned u; } v; v.f = f;
    unsigned r = v.u + 0x7fffu + ((v.u >> 16) & 1u);   // RNE
    return (short)(r >> 16);
}

__device__ __forceinline__ f4v mfma16(s8v a, s8v b, f4v c) {
    return __builtin_amdgcn_mfma_f32_16x16x32_bf16(a, b, c, 0, 0, 0);
}
__device__ __forceinline__ f16v mfma32(s8v a, s8v b, f16v c) {
    return __builtin_amdgcn_mfma_f32_32x32x16_bf16(a, b, c, 0, 0, 0);
}

__device__ __forceinline__ void glds16(const short* g, short* l) {
    __builtin_amdgcn_global_load_lds(
        (const __attribute__((address_space(1))) void*)g,
        (__attribute__((address_space(3))) void*)l, 16, 0, 0);
}

// counted-vmcnt barrier: do NOT drain the in-flight prefetch (T4).
#define WAITBAR(NLIT)                                                       \
    do {                                                                    \
        __builtin_amdgcn_sched_barrier(0);                                  \
        asm volatile("s_waitcnt vmcnt(" NLIT ")" ::: "memory");             \
        __builtin_amdgcn_s_barrier();                                       \
        __builtin_amdgcn_sched_barrier(0);                                  \
    } while (0)

// ---------------- weight transpose + f32->bf16 ----------------
__global__ void transpose_cvt(const float* __restrict__ src, short* __restrict__ dst,
                              int K, int N) {
    __shared__ float tile[32][33];
    const int l = blockIdx.z;
    src += (size_t)l * K * N;
    dst += (size_t)l * N * K;
    const int n0 = blockIdx.x * 32, k0 = blockIdx.y * 32;
    const int tx = threadIdx.x, ty = threadIdx.y;   // 32 x 8
    #pragma unroll
    for (int i = 0; i < 32; i += 8)
        tile[ty + i][tx] = src[(size_t)(k0 + ty + i) * N + n0 + tx];
    __syncthreads();
    #pragma unroll
    for (int i = 0; i < 32; i += 8)
        dst[(size_t)(n0 + ty + i) * K + k0 + tx] = f2bf(tile[tx][ty + i]);
}

// ---------------- LayerNorm: x f32 [NTOK][256] -> bf16 ----------------
__global__ void ln_kernel(const float* __restrict__ x, const float* __restrict__ g,
                          const float* __restrict__ b, short* __restrict__ out) {
    const int row  = blockIdx.x * 4 + (threadIdx.x >> 6);
    const int lane = threadIdx.x & 63;
    const float4 v = *(const float4*)(x + (size_t)row * DMODEL + lane * 4);
    float s = v.x + v.y + v.z + v.w;
    #pragma unroll
    for (int m = 32; m; m >>= 1) s += __shfl_xor(s, m);
    const float mean = s * (1.0f / DMODEL);
    const float dx = v.x - mean, dy = v.y - mean, dz = v.z - mean, dw = v.w - mean;
    float q = dx*dx + dy*dy + dz*dz + dw*dw;
    #pragma unroll
    for (int m = 32; m; m >>= 1) q += __shfl_xor(q, m);
    const float rstd = rsqrtf(q * (1.0f / DMODEL) + 1e-5f);
    const float4 gg = *(const float4*)(g + lane * 4);
    const float4 bb = *(const float4*)(b + lane * 4);
    s4v o;
    o.x = f2bf(dx * rstd * gg.x + bb.x);
    o.y = f2bf(dy * rstd * gg.y + bb.y);
    o.z = f2bf(dz * rstd * gg.z + bb.z);
    o.w = f2bf(dw * rstd * gg.w + bb.w);
    *(s4v*)(out + (size_t)row * DMODEL + lane * 4) = o;
}

#define EPI_QKV  0
#define EPI_RES  1
#define EPI_GELU 2

// -------- shared epilogue (verified R4-R14; EPI_RES gains separate resin) ------
template<int EPI>
__device__ __forceinline__ void gemm_epilogue(
        f4v acc[2][2], int trow0, int col0, int N, int g, int c,
        const float* __restrict__ bias,
        const float* __restrict__ resin, float* __restrict__ resout,
        short* __restrict__ outb,
        short* __restrict__ qb, short* __restrict__ kb, short* __restrict__ vtb) {
    if (EPI == EPI_QKV) {
        #pragma unroll
        for (int mf = 0; mf < 2; mf++) {
            const int tokb = trow0 + mf * 16 + g * 4;
            const int b = tokb >> 11, n = tokb & 2047;
            #pragma unroll
            for (int nf = 0; nf < 2; nf++) {
                const int colg = col0 + nf * 16 + c;
                const int part = colg >> 8, pc = colg & 255;
                const int h = pc >> 5, d = pc & 31;
                const size_t bh = (size_t)(b * NH + h);
                if (part == 2) {
                    s4v pv;
                    #pragma unroll
                    for (int r = 0; r < 4; r++) pv[r] = f2bf(acc[mf][nf][r]);
                    *(s4v*)(vtb + (bh * 32 + d) * SEQ + n) = pv;
                } else {
                    // q pre-scaled by dim^-0.5 * log2(e) so attention can exp2 raw scores
                    const float sc = (part == 0) ? 0.090168440f : 1.0f;
                    short* dst = (part == 0 ? qb : kb) + ((bh << 11) + n) * 32 + d;
                    #pragma unroll
                    for (int r = 0; r < 4; r++) dst[(size_t)r * 32] = f2bf(acc[mf][nf][r] * sc);
                }
            }
        }
    } else if (EPI == EPI_RES) {
        #pragma unroll
        for (int mf = 0; mf < 2; mf++)
            #pragma unroll
            for (int nf = 0; nf < 2; nf++) {
                const int colg = col0 + nf * 16 + c;
                const float bv = bias[colg];
                #pragma unroll
                for (int r = 0; r < 4; r++) {
                    const int row = trow0 + mf * 16 + g * 4 + r;
                    const size_t idx = (size_t)row * N + colg;
                    resout[idx] = resin[idx] + bv + acc[mf][nf][r];
                }
            }
    } else {  // EPI_GELU
        #pragma unroll
        for (int mf = 0; mf < 2; mf++)
            #pragma unroll
            for (int nf = 0; nf < 2; nf++) {
                const int colg = col0 + nf * 16 + c;
                const float bv = bias[colg];
                #pragma unroll
                for (int r = 0; r < 4; r++) {
                    const int row = trow0 + mf * 16 + g * 4 + r;
                    const float v = acc[mf][nf][r] + bv;
                    const float ge = 0.5f * v * (1.0f + erff(v * 0.70710678118f));
                    outb[(size_t)row * N + colg] = f2bf(ge);
                }
            }
    }
}

// ---------------- K=256 GEMM: 3-buffer counted-vmcnt pipeline (R8-verified) ----
template<int EPI>
__global__ __launch_bounds__(256) void gemm_p256(
        const short* __restrict__ A, const short* __restrict__ Bt,
        const int N, const int nbx,
        const float* __restrict__ bias,
        const float* __restrict__ resin, float* __restrict__ resout,
        short* __restrict__ outb,
        short* __restrict__ qb, short* __restrict__ kb, short* __restrict__ vtb) {
    __shared__ short ldsA[3][64 * 64];
    __shared__ short ldsB[3][64 * 64];
    const int nblk = gridDim.x;
    const int bid  = blockIdx.x;
    const int swz  = (bid & 7) * (nblk >> 3) + (bid >> 3);   // XCD-chunked
    const int m0 = (swz / nbx) * 64, n0 = (swz % nbx) * 64;
    const int tid  = threadIdx.x;
    const int wave = tid >> 6, lane = tid & 63;
    const int g = lane >> 4, c = lane & 15;
    const int wm = wave >> 1, wn = wave & 1;

#define STAGEP(buf, k0)                                                     \
    do {                                                                    \
        _Pragma("unroll")                                                   \
        for (int i = 0; i < 2; i++) {                                       \
            const int idx = i * 256 + tid;                                  \
            const int row = idx >> 3, c8 = idx & 7;                         \
            const int gcol = (k0) + ((c8 ^ (row & 7)) * 8);                 \
            glds16(A  + (size_t)(m0 + row) * 256 + gcol, &ldsA[buf][idx*8]);\
            glds16(Bt + (size_t)(n0 + row) * 256 + gcol, &ldsB[buf][idx*8]);\
        }                                                                   \
    } while (0)

#define COMPUTE(buf)                                                        \
    do {                                                                    \
        _Pragma("unroll")                                                   \
        for (int kk = 0; kk < 2; kk++) {                                    \
            s8v af[2], bfr[2];                                              \
            _Pragma("unroll")                                               \
            for (int mf = 0; mf < 2; mf++)                                  \
                af[mf] = *(const s8v*)(&ldsA[buf][(wm*32+mf*16+c)*64 +      \
                                        (((kk<<2)+g) ^ (c&7)) * 8]);        \
            _Pragma("unroll")                                               \
            for (int nf = 0; nf < 2; nf++)                                  \
                bfr[nf] = *(const s8v*)(&ldsB[buf][(wn*32+nf*16+c)*64 +     \
                                        (((kk<<2)+g) ^ (c&7)) * 8]);        \
            _Pragma("unroll")                                               \
            for (int mf = 0; mf < 2; mf++)                                  \
                _Pragma("unroll")                                           \
                for (int nf = 0; nf < 2; nf++)                              \
                    acc[mf][nf] = mfma16(af[mf], bfr[nf], acc[mf][nf]);     \
        }                                                                   \
    } while (0)

    f4v acc[2][2];
    #pragma unroll
    for (int i = 0; i < 2; i++)
        #pragma unroll
        for (int j = 0; j < 2; j++) acc[i][j] = (f4v){0.f, 0.f, 0.f, 0.f};

    STAGEP(0, 0);
    STAGEP(1, 64);
    WAITBAR("4");
    STAGEP(2, 128);
    COMPUTE(0);
    WAITBAR("4");
    STAGEP(0, 192);
    COMPUTE(1);
    WAITBAR("4");
    COMPUTE(2);
    WAITBAR("0");
    COMPUTE(0);
#undef STAGEP
#undef COMPUTE

    gemm_epilogue<EPI>(acc, m0 + wm * 32, n0 + wn * 32, N, g, c,
                       bias, resin, resout, outb, qb, kb, vtb);
}

// ---------------- K=1024 GEMM (FFN2): rolling 3-buffer counted-vmcnt ----------
template<int EPI>
__global__ __launch_bounds__(256) void gemm_p1024(
        const short* __restrict__ A, const short* __restrict__ Bt,
        const int N, const int nbx,
        const float* __restrict__ bias,
        const float* __restrict__ resin, float* __restrict__ resout,
        short* __restrict__ outb) {
    __shared__ short ldsA[3][64 * 64];
    __shared__ short ldsB[3][64 * 64];
    const int nblk = gridDim.x;
    const int bid  = blockIdx.x;
    const int swz  = (bid & 7) * (nblk >> 3) + (bid >> 3);
    const int m0 = (swz / nbx) * 64, n0 = (swz % nbx) * 64;
    const int tid  = threadIdx.x;
    const int wave = tid >> 6, lane = tid & 63;
    const int g = lane >> 4, c = lane & 15;
    const int wm = wave >> 1, wn = wave & 1;

#define STAGEK(buf, k0)                                                     \
    do {                                                                    \
        _Pragma("unroll")                                                   \
        for (int i = 0; i < 2; i++) {                                       \
            const int idx = i * 256 + tid;                                  \
            const int row = idx >> 3, c8 = idx & 7;                         \
            const int gcol = (k0) + ((c8 ^ (row & 7)) * 8);                 \
            glds16(A  + (size_t)(m0 + row) * 1024 + gcol, &ldsA[buf][idx*8]);\
            glds16(Bt + (size_t)(n0 + row) * 1024 + gcol, &ldsB[buf][idx*8]);\
        }                                                                   \
    } while (0)

#define COMPUTE(buf)                                                        \
    do {                                                                    \
        _Pragma("unroll")                                                   \
        for (int kk = 0; kk < 2; kk++) {                                    \
            s8v af[2], bfr[2];                                              \
            _Pragma("unroll")                                               \
            for (int mf = 0; mf < 2; mf++)                                  \
                af[mf] = *(const s8v*)(&ldsA[buf][(wm*32+mf*16+c)*64 +      \
                                        (((kk<<2)+g) ^ (c&7)) * 8]);        \
            _Pragma("unroll")                                               \
            for (int nf = 0; nf < 2; nf++)                                  \
                bfr[nf] = *(const s8v*)(&ldsB[buf][(wn*32+nf*16+c)*64 +     \
                                        (((kk<<2)+g) ^ (c&7)) * 8]);        \
            _Pragma("unroll")                                               \
            for (int mf = 0; mf < 2; mf++)                                  \
                _Pragma("unroll")                                           \
                for (int nf = 0; nf < 2; nf++)                              \
                    acc[mf][nf] = mfma16(af[mf], bfr[nf], acc[mf][nf]);     \
        }                                                                   \
    } while (0)

    f4v acc[2][2];
    #pragma unroll
    for (int i = 0; i < 2; i++)
        #pragma unroll
        for (int j = 0; j < 2; j++) acc[i][j] = (f4v){0.f, 0.f, 0.f, 0.f};

    STAGEK(0, 0);
    STAGEK(1, 64);
    WAITBAR("4");
    int b0 = 0, b1 = 1, b2 = 2;
    for (int t = 0; t < 16; ++t) {
        if (t + 2 < 16) STAGEK(b2, (t + 2) * 64);
        COMPUTE(b0);
        if (t + 2 < 16)      WAITBAR("4");
        else if (t == 14)    WAITBAR("0");
        const int tmp = b0; b0 = b1; b1 = b2; b2 = tmp;
    }
#undef STAGEK
#undef COMPUTE

    gemm_epilogue<EPI>(acc, m0 + wm * 32, n0 + wn * 32, N, g, c,
                       bias, resin, resout, outb, nullptr, nullptr, nullptr);
}

// ---------------- flash attention: R14 structure + T5 setprio ----------------
// 4 waves x 32q, shared K/V in LDS, 3-buffer counted-vmcnt, 128-kv phases,
// hardware cvt_pk packing, fully unrolled, setprio(1) around compute cluster.
__global__ __launch_bounds__(256) void attn_kernel(
        const short* __restrict__ qb, const short* __restrict__ kb,
        const short* __restrict__ vtb, short* __restrict__ out) {
    __shared__ short ldsK[3][4096];   // [buf][2 tiles x 256 slots][8]
    __shared__ short ldsV[3][4096];
    const int bh = blockIdx.y;
    const int tid = threadIdx.x;
    const int wave = tid >> 6, lane = tid & 63;
    const int ql = lane & 31;       // q column this lane owns
    const int h2 = lane >> 5;       // lane half (contraction sub-block)
    const int q0 = blockIdx.x * 128 + wave * 32;
    const short* Q  = qb  + (size_t)bh * SEQ * HD;
    const short* Kp = kb  + (size_t)bh * SEQ * HD;
    const short* Vt = vtb + (size_t)bh * HD * SEQ;

    const s8v qf1 = *(const s8v*)(Q + (size_t)(q0 + ql) * HD + 8 * h2);
    const s8v qf2 = *(const s8v*)(Q + (size_t)(q0 + ql) * HD + 16 + 8 * h2);
    const s8v ones = (s8v){0x3F80,0x3F80,0x3F80,0x3F80,0x3F80,0x3F80,0x3F80,0x3F80};

    const f16v zero = {};
    f16v o   = zero;                // O^T[d][q] accumulator
    f16v lsv = zero;                // every reg = running sum_k P[k][q]

    const short* gK = Kp + (size_t)(tid & 63) * HD + (tid >> 6) * 8;
    const short* gV = Vt + (size_t)(tid & 31) * SEQ + (tid >> 5) * 8;

#define ASTAGE(buf, kt)                                                     \
    do {                                                                    \
        glds16(gK + (size_t)(kt) * HD,        &ldsK[buf][tid * 8]);         \
        glds16(gK + (size_t)((kt) + 64) * HD, &ldsK[buf][(256 + tid) * 8]); \
        glds16(gV + (kt),                     &ldsV[buf][tid * 8]);         \
        glds16(gV + (kt) + 64,                &ldsV[buf][(256 + tid) * 8]); \
    } while (0)

#define ATILE(buf, ti)                                                      \
    do {                                                                    \
        _Pragma("unroll")                                                   \
        for (int kk = 0; kk < 2; kk++) {                                    \
            const s8v ka1 = *(const s8v*)(&ldsK[buf][((ti)*256 + kk*32 + ql + 64*h2) * 8]);        \
            const s8v ka2 = *(const s8v*)(&ldsK[buf][((ti)*256 + kk*32 + ql + 128 + 64*h2) * 8]);  \
            f16v s_ = mfma32(ka1, qf1, zero);                               \
            s_ = mfma32(ka2, qf2, s_);                                      \
            float pr_[16];                                                  \
            _Pragma("unroll")                                               \
            for (int r = 0; r < 16; r++) pr_[r] = EXP2(s_[r]);              \
            int w_[8];                                                      \
            _Pragma("unroll")                                               \
            for (int i = 0; i < 8; i++)                                     \
                asm("v_cvt_pk_bf16_f32 %0, %1, %2"                          \
                    : "=v"(w_[i]) : "v"(pr_[2*i]), "v"(pr_[2*i+1]));        \
            asm("v_permlane32_swap_b32 %0, %1" : "+v"(w_[0]), "+v"(w_[2])); \
            asm("v_permlane32_swap_b32 %0, %1" : "+v"(w_[1]), "+v"(w_[3])); \
            asm("v_permlane32_swap_b32 %0, %1" : "+v"(w_[4]), "+v"(w_[6])); \
            asm("v_permlane32_swap_b32 %0, %1" : "+v"(w_[5]), "+v"(w_[7])); \
            union { int i[4]; s8v v; } B1_, B2_;                            \
            B1_.i[0]=w_[0]; B1_.i[1]=w_[1]; B1_.i[2]=w_[2]; B1_.i[3]=w_[3]; \
            B2_.i[0]=w_[4]; B2_.i[1]=w_[5]; B2_.i[2]=w_[6]; B2_.i[3]=w_[7]; \
            lsv = mfma32(ones, B1_.v, lsv);                                 \
            lsv = mfma32(ones, B2_.v, lsv);                                 \
            const s8v va1 = *(const s8v*)(&ldsV[buf][((ti)*256 + ql + 128*kk + 32*h2) * 8]);       \
            const s8v va2 = *(const s8v*)(&ldsV[buf][((ti)*256 + ql + 128*kk + 64 + 32*h2) * 8]);  \
            o = mfma32(va1, B1_.v, o);                                      \
            o = mfma32(va2, B2_.v, o);                                      \
        }                                                                   \
    } while (0)

    ASTAGE(0, 0);
    ASTAGE(1, 128);
    WAITBAR("4");                       // phase 0 landed; phase 1 in flight
    #pragma unroll
    for (int ph = 0; ph < 16; ++ph) {
        const int cbuf = ph % 3;
        const int nbuf = (ph + 2) % 3;
        if (ph + 2 < 16) ASTAGE(nbuf, (ph + 2) * 128);
        __builtin_amdgcn_s_setprio(1);
        ATILE(cbuf, 0);
        ATILE(cbuf, 1);
        __builtin_amdgcn_s_setprio(0);
        if (ph + 2 < 16)      WAITBAR("4");   // phase ph+1 landed, ph+2 in flight
        else if (ph == 14)    WAITBAR("0");   // last phase landed
    }
#undef ASTAGE
#undef ATILE

    // direct epilogue: lane (ql,h2) holds o[r] for d=(r&3)+8*(r>>2)+4*h2, q=ql
    const int b = bh >> 3, hh = bh & 7;
    const float inv = 1.0f / lsv[0];
    const size_t rowoff = (size_t)(b * SEQ + q0 + ql) * DMODEL + hh * HD;
    #pragma unroll
    for (int rr = 0; rr < 4; rr++) {
        union { int i[2]; s4v v; } uo;
        const float e0 = o[4*rr]   * inv, e1 = o[4*rr+1] * inv;
        const float e2 = o[4*rr+2] * inv, e3 = o[4*rr+3] * inv;
        asm("v_cvt_pk_bf16_f32 %0, %1, %2" : "=v"(uo.i[0]) : "v"(e0), "v"(e1));
        asm("v_cvt_pk_bf16_f32 %0, %1, %2" : "=v"(uo.i[1]) : "v"(e2), "v"(e3));
        *(s4v*)(out + rowoff + 8 * rr + 4 * h2) = uo.v;
    }
}

// -------------------------------- launcher --------------------------------
extern "C" void kernel_launch(void* const* d_in, const int* in_sizes, int n_in,
                              void* d_out, int out_size, void* d_ws, size_t ws_size,
                              hipStream_t stream) {
    const float* x0    = (const float*)d_in[0];
    const float* w_qkv = (const float*)d_in[3];
    const float* w_out = (const float*)d_in[4];
    const float* b_out = (const float*)d_in[5];
    const float* w1    = (const float*)d_in[8];
    const float* b1    = (const float*)d_in[9];
    const float* w2    = (const float*)d_in[10];
    const float* b2    = (const float*)d_in[11];
    const float* ln1_g = (const float*)d_in[1];
    const float* ln1_b = (const float*)d_in[2];
    const float* ln2_g = (const float*)d_in[6];
    const float* ln2_b = (const float*)d_in[7];
    float* xout = (float*)d_out;

    short* ws    = (short*)d_ws;
    short* xn    = ws;
    short* qb    = xn    + (size_t)NTOK * DMODEL;
    short* kb    = qb    + (size_t)BATCH * NH * SEQ * HD;
    short* vtb   = kb    + (size_t)BATCH * NH * SEQ * HD;
    short* ao    = vtb   + (size_t)BATCH * NH * SEQ * HD;
    short* mid   = ao    + (size_t)NTOK * DMODEL;
    short* wqkvT = mid   + (size_t)NTOK * MLPD;
    short* woutT = wqkvT + (size_t)DEPTH * 3 * DMODEL * DMODEL;
    short* w1T   = woutT + (size_t)DEPTH * DMODEL * DMODEL;
    short* w2T   = w1T   + (size_t)DEPTH * MLPD * DMODEL;

    transpose_cvt<<<dim3(3*DMODEL/32, DMODEL/32, DEPTH), dim3(32, 8), 0, stream>>>(
        w_qkv, wqkvT, DMODEL, 3*DMODEL);
    transpose_cvt<<<dim3(DMODEL/32, DMODEL/32, DEPTH), dim3(32, 8), 0, stream>>>(
        w_out, woutT, DMODEL, DMODEL);
    transpose_cvt<<<dim3(MLPD/32, DMODEL/32, DEPTH), dim3(32, 8), 0, stream>>>(
        w1, w1T, DMODEL, MLPD);
    transpose_cvt<<<dim3(DMODEL/32, MLPD/32, DEPTH), dim3(32, 8), 0, stream>>>(
        w2, w2T, MLPD, DMODEL);

    for (int l = 0; l < DEPTH; l++) {
        // layer 0 reads the residual stream from d_in[0] directly (never mutated)
        const float* resx = (l == 0) ? x0 : xout;
        ln_kernel<<<NTOK/4, 256, 0, stream>>>(resx, ln1_g + l*DMODEL, ln1_b + l*DMODEL, xn);
        gemm_p256<EPI_QKV><<<1536, 256, 0, stream>>>(
            xn, wqkvT + (size_t)l * 3 * DMODEL * DMODEL,
            3*DMODEL, 12, nullptr, nullptr, nullptr, nullptr, qb, kb, vtb);
        attn_kernel<<<dim3(SEQ/128, BATCH*NH), 256, 0, stream>>>(qb, kb, vtb, ao);
        gemm_p256<EPI_RES><<<512, 256, 0, stream>>>(
            ao, woutT + (size_t)l * DMODEL * DMODEL,
            DMODEL, 4, b_out + l*DMODEL, resx, xout, nullptr, nullptr, nullptr, nullptr);
        ln_kernel<<<NTOK/4, 256, 0, stream>>>(xout, ln2_g + l*DMODEL, ln2_b + l*DMODEL, xn);
        gemm_p256<EPI_GELU><<<2048, 256, 0, stream>>>(
            xn, w1T + (size_t)l * MLPD * DMODEL,
            MLPD, 16, b1 + l*MLPD, nullptr, nullptr, mid, nullptr, nullptr, nullptr);
        gemm_p1024<EPI_RES><<<512, 256, 0, stream>>>(
            mid, w2T + (size_t)l * DMODEL * MLPD,
            DMODEL, 4, b2 + l*DMODEL, xout, xout, nullptr);
    }
}